// Round 3
// baseline (298.484 us; speedup 1.0000x reference)
//
#include <hip/hip_runtime.h>

// GAT attention weights (heads=1) for two block-diagonal graphs.
// Output = softmax-by-dst of leakyrelu(a_s[src]+a_d[dst]) over N*N edges.
//
// R3: k3's LDS f32 atomicAdd removed. R2 counters showed 3.54 cyc/edge with
// all pipes idle == LDS-atomic lane throughput (~3.5 cyc/lane serialized).
// Replacement: wave-private bins (no cross-wave race) + non-atomic RMW;
// intra-wave same-instruction collisions resolved by a volatile tag array
// (write lane-id, read back, unique winner commits; losers retry; capped
// fallback to atomicAdd). Both edge kernels get double-buffered index-stream
// prefetch to break just-in-time load serialization (VGPR was 12!).
//
// No segment-max: logits bounded ~7.2 -> exp <= ~1400, safe in fp32.

#define NNODES 4096
#define NSEG   8192
#define NEG_SLOPE 0.2f

#define K3_TPB 256
#define K3_QPB 8192          // int4-quads per k3 block = 32768 edges
#define K5_TPB 512
#define K5_QPB 8192          // quads per k5 block = 32768 edges

__global__ void k1_wvec(const float* __restrict__ W,
                        const float* __restrict__ att_src,
                        const float* __restrict__ att_dst,
                        float* __restrict__ wvs, float* __restrict__ wvd) {
    int f = threadIdx.x;
    const float* row = W + f * 128;
    float s = 0.f, d = 0.f;
    #pragma unroll 8
    for (int j = 0; j < 128; ++j) {
        float w = row[j];
        s += w * att_src[j];
        d += w * att_dst[j];
    }
    wvs[f] = s; wvd[f] = d;
}

__global__ void k2_logits(const float* __restrict__ x1, const float* __restrict__ x2,
                          const float* __restrict__ wvs, const float* __restrict__ wvd,
                          float* __restrict__ a_s, float* __restrict__ a_d) {
    int wave = blockIdx.x * 4 + (threadIdx.x >> 6);
    int lane = threadIdx.x & 63;
    const float* xrow = (wave < NNODES) ? (x1 + (size_t)wave * 256)
                                        : (x2 + (size_t)(wave - NNODES) * 256);
    float4 xv  = ((const float4*)xrow)[lane];
    float4 wsv = ((const float4*)wvs)[lane];
    float4 wdv = ((const float4*)wvd)[lane];
    float ps = xv.x*wsv.x + xv.y*wsv.y + xv.z*wsv.z + xv.w*wsv.w;
    float pd = xv.x*wdv.x + xv.y*wdv.y + xv.z*wdv.z + xv.w*wdv.w;
    #pragma unroll
    for (int o = 32; o > 0; o >>= 1) {
        ps += __shfl_down(ps, o);
        pd += __shfl_down(pd, o);
    }
    if (lane == 0) { a_s[wave] = ps; a_d[wave] = pd; }
}

__device__ __forceinline__ float lrelu_exp(float e) {
    e = (e > 0.f) ? e : NEG_SLOPE * e;
    return __expf(e);
}

__global__ __launch_bounds__(K3_TPB) void k3_denom(
        const int* __restrict__ ei1, const int* __restrict__ ei2,
        const float* __restrict__ a_s, const float* __restrict__ a_d,
        float* __restrict__ partials, int E1, int g1_blocks) {
    __shared__ float bins[4][NNODES];        // 64 KB, wave-private regions
    __shared__ int   tag[NNODES];            // 16 KB, shared collision filter
    __shared__ float las[NNODES];            // 16 KB
    __shared__ float lad[NNODES];            // 16 KB  -> 112 KB total
    volatile int* vtag = tag;

    int t = threadIdx.x;
    float* binw = bins[t >> 6];

    int b = blockIdx.x;
    const int* sp; int qbase, nodeoff;
    if (b < g1_blocks) { sp = ei1; qbase = b * K3_QPB; nodeoff = 0; }
    else               { sp = ei2; qbase = (b - g1_blocks) * K3_QPB; nodeoff = NNODES; }
    const int4* s4 = (const int4*)sp;
    const int4* d4 = (const int4*)(sp + E1);

    // stage logits (1024 float4 each) + zero bins (4096 float4)
    #pragma unroll
    for (int i = 0; i < 4; ++i) {
        ((float4*)las)[t + i*K3_TPB] = ((const float4*)(a_s + nodeoff))[t + i*K3_TPB];
        ((float4*)lad)[t + i*K3_TPB] = ((const float4*)(a_d + nodeoff))[t + i*K3_TPB];
    }
    #pragma unroll
    for (int i = 0; i < 16; ++i)
        ((float4*)&bins[0][0])[t + i*K3_TPB] = make_float4(0.f,0.f,0.f,0.f);
    __syncthreads();

    auto insert = [&](int d, float val) {
        bool pending = true;
        int rounds = 0;
        while (__any(pending)) {
            if (++rounds > 8) {                 // safety cap (cross-wave tag stomping)
                if (pending) atomicAdd(&binw[d], val);
                break;
            }
            if (pending) vtag[d] = t;           // claim
            if (pending && vtag[d] == t) {      // unique same-wave winner commits
                binw[d] += val;                 // non-atomic: region is wave-private
                pending = false;
            }
        }
    };

    // double-buffered batches: 32 quads/thread = 8 batches of 4
    int4 sbuf[2][4], dbuf[2][4];
    #pragma unroll
    for (int i = 0; i < 4; ++i) {
        int q = qbase + i*K3_TPB + t;
        sbuf[0][i] = s4[q]; dbuf[0][i] = d4[q];
    }
    #pragma unroll
    for (int bt = 0; bt < 8; ++bt) {
        int cur = bt & 1, nxt = cur ^ 1;
        if (bt < 7) {
            #pragma unroll
            for (int i = 0; i < 4; ++i) {
                int q = qbase + ((bt+1)*4 + i)*K3_TPB + t;
                sbuf[nxt][i] = s4[q]; dbuf[nxt][i] = d4[q];
            }
        }
        #pragma unroll
        for (int i = 0; i < 4; ++i) {
            int4 sv = sbuf[cur][i], dv = dbuf[cur][i];
            float e0 = las[sv.x] + lad[dv.x];
            float e1 = las[sv.y] + lad[dv.y];
            float e2 = las[sv.z] + lad[dv.z];
            float e3 = las[sv.w] + lad[dv.w];
            float v0 = lrelu_exp(e0), v1 = lrelu_exp(e1);
            float v2 = lrelu_exp(e2), v3 = lrelu_exp(e3);
            insert(dv.x, v0); insert(dv.y, v1);
            insert(dv.z, v2); insert(dv.w, v3);
        }
    }
    __syncthreads();

    // merge 4 wave regions -> partials[b][*]
    float* pb = partials + (size_t)b * NNODES;
    #pragma unroll
    for (int i = 0; i < 4; ++i) {
        int c = t + i*K3_TPB;                   // float4 index, 1024 total
        float4 s0 = ((float4*)bins[0])[c];
        float4 s1 = ((float4*)bins[1])[c];
        float4 s2 = ((float4*)bins[2])[c];
        float4 s3 = ((float4*)bins[3])[c];
        float4 r;
        r.x = s0.x+s1.x+s2.x+s3.x;
        r.y = s0.y+s1.y+s2.y+s3.y;
        r.z = s0.z+s1.z+s2.z+s3.z;
        r.w = s0.w+s1.w+s2.w+s3.w;
        ((float4*)pb)[c] = r;
    }
}

__global__ void k4a_reduce(const float* __restrict__ partials,
                           float* __restrict__ partials2, int g1_blocks) {
    int tid = blockIdx.x * blockDim.x + threadIdx.x;
    int c  = tid >> 13;
    int sg = tid & (NSEG - 1);
    int bpc = g1_blocks >> 3;
    int b0 = ((sg < NNODES) ? 0 : g1_blocks) + c * bpc;
    int col = sg & (NNODES - 1);
    float s = 0.f;
    for (int j = 0; j < bpc; ++j)
        s += partials[(size_t)(b0 + j) * NNODES + col];
    partials2[tid] = s;
}

__global__ void k4b_inv(const float* __restrict__ partials2,
                        float* __restrict__ inv_denom) {
    int sg = blockIdx.x * blockDim.x + threadIdx.x;
    float s = 0.f;
    #pragma unroll
    for (int c = 0; c < 8; ++c) s += partials2[c * NSEG + sg];
    inv_denom[sg] = 1.0f / s;
}

__global__ __launch_bounds__(K5_TPB) void k5_alpha(
        const int* __restrict__ ei1, const int* __restrict__ ei2,
        const float* __restrict__ a_s, const float* __restrict__ a_d,
        const float* __restrict__ inv_denom,
        float* __restrict__ out, int E1, int g1_blocks) {
    __shared__ float las[NNODES];
    __shared__ float lad[NNODES];
    __shared__ float linv[NNODES];           // 48 KB total
    int t = threadIdx.x;
    int b = blockIdx.x;
    const int* sp; int qbase, outq, nodeoff;
    if (b < g1_blocks) { sp = ei1; qbase = b * K5_QPB; outq = qbase; nodeoff = 0; }
    else { sp = ei2; qbase = (b - g1_blocks) * K5_QPB; outq = E1/4 + qbase; nodeoff = NNODES; }
    const int4* s4 = (const int4*)sp;
    const int4* d4 = (const int4*)(sp + E1);

    #pragma unroll
    for (int i = 0; i < 2; ++i) {
        ((float4*)las)[t + i*K5_TPB]  = ((const float4*)(a_s + nodeoff))[t + i*K5_TPB];
        ((float4*)lad)[t + i*K5_TPB]  = ((const float4*)(a_d + nodeoff))[t + i*K5_TPB];
        ((float4*)linv)[t + i*K5_TPB] = ((const float4*)(inv_denom + nodeoff))[t + i*K5_TPB];
    }
    __syncthreads();

    float4* out4 = (float4*)out;
    int4 sbuf[2][4], dbuf[2][4];
    #pragma unroll
    for (int i = 0; i < 4; ++i) {
        int q = qbase + i*K5_TPB + t;
        sbuf[0][i] = s4[q]; dbuf[0][i] = d4[q];
    }
    #pragma unroll
    for (int bt = 0; bt < 4; ++bt) {
        int cur = bt & 1, nxt = cur ^ 1;
        if (bt < 3) {
            #pragma unroll
            for (int i = 0; i < 4; ++i) {
                int q = qbase + ((bt+1)*4 + i)*K5_TPB + t;
                sbuf[nxt][i] = s4[q]; dbuf[nxt][i] = d4[q];
            }
        }
        #pragma unroll
        for (int i = 0; i < 4; ++i) {
            int4 sv = sbuf[cur][i], dv = dbuf[cur][i];
            float4 r;
            r.x = lrelu_exp(las[sv.x] + lad[dv.x]) * linv[dv.x];
            r.y = lrelu_exp(las[sv.y] + lad[dv.y]) * linv[dv.y];
            r.z = lrelu_exp(las[sv.z] + lad[dv.z]) * linv[dv.z];
            r.w = lrelu_exp(las[sv.w] + lad[dv.w]) * linv[dv.w];
            out4[outq + (bt*4 + i)*K5_TPB + t] = r;
        }
    }
}

extern "C" void kernel_launch(void* const* d_in, const int* in_sizes, int n_in,
                              void* d_out, int out_size, void* d_ws, size_t ws_size,
                              hipStream_t stream) {
    const float* x1      = (const float*)d_in[0];
    const float* x2      = (const float*)d_in[1];
    const int*   ei1     = (const int*)d_in[2];
    const int*   ei2     = (const int*)d_in[3];
    const float* W       = (const float*)d_in[4];
    const float* att_src = (const float*)d_in[5];
    const float* att_dst = (const float*)d_in[6];
    float* out = (float*)d_out;

    const int E1 = in_sizes[2] / 2;          // 8388608 edges per graph

    float* wsf       = (float*)d_ws;
    float* wvs       = wsf;                  // 256
    float* wvd       = wsf + 256;            // 256
    float* a_s       = wsf + 512;            // 8192
    float* a_d       = wsf + 512 + NSEG;     // 8192
    float* inv_denom = wsf + 512 + 2*NSEG;   // 8192
    float* partials2 = wsf + 32768;          // 65536
    float* partials  = wsf + 131072;         // 512*4096 floats (8 MB)

    hipLaunchKernelGGL(k1_wvec, dim3(1), dim3(256), 0, stream,
                       W, att_src, att_dst, wvs, wvd);
    hipLaunchKernelGGL(k2_logits, dim3(2 * NNODES / 4), dim3(256), 0, stream,
                       x1, x2, wvs, wvd, a_s, a_d);

    int g1b3 = (E1 / 4) / K3_QPB;            // 256
    hipLaunchKernelGGL(k3_denom, dim3(2 * g1b3), dim3(K3_TPB), 0, stream,
                       ei1, ei2, a_s, a_d, partials, E1, g1b3);
    hipLaunchKernelGGL(k4a_reduce, dim3(8 * NSEG / 256), dim3(256), 0, stream,
                       partials, partials2, g1b3);
    hipLaunchKernelGGL(k4b_inv, dim3(NSEG / 256), dim3(256), 0, stream,
                       partials2, inv_denom);

    int g1b5 = (E1 / 4) / K5_QPB;            // 256
    hipLaunchKernelGGL(k5_alpha, dim3(2 * g1b5), dim3(K5_TPB), 0, stream,
                       ei1, ei2, a_s, a_d, inv_denom, out, E1, g1b5);
}

// Round 5
// 271.693 us; speedup vs baseline: 1.0986x; 1.0986x over previous
//
#include <hip/hip_runtime.h>

// GAT attention weights (heads=1) for two block-diagonal graphs.
// Output = softmax-by-dst of leakyrelu(a_s[src]+a_d[dst]) over N*N edges.
//
// R5 = R4 design with the staging-loop bug fixed (R4 kept i<4 iteration
// counts from a 256-thread version after moving to 1024 threads -> 64KB
// writes into 16KB LDS arrays; NNODES floats == exactly 1024 float4 ==
// ONE iteration at 1024 threads).
//
// Model: random-address LDS lane-ops ~1.2 cyc (read or atomic) on the LDS
// pipe; divergent L1-hit global gathers ~2 cyc/lane on the separate TA pipe.
//  k3: a_s[src] via LDS, a_d[dst] via global/L1, LDS-atomic accumulate,
//      stream ex to d_out (write pipe idle).
//  k5: stream ex back + ONE LDS gather (inv_denom[dst]) + in-place write.
//
// No segment-max: logits bounded ~7.2 -> exp <= ~1400, safe in fp32.

#define NNODES 4096
#define NSEG   8192
#define NEG_SLOPE 0.2f
#define EK_TPB 1024
#define EK_QPB 8192          // int4 quads per edge-kernel block = 32768 edges

__global__ void k1_wvec(const float* __restrict__ W,
                        const float* __restrict__ att_src,
                        const float* __restrict__ att_dst,
                        float* __restrict__ wvs, float* __restrict__ wvd) {
    int f = threadIdx.x;
    const float* row = W + f * 128;
    float s = 0.f, d = 0.f;
    #pragma unroll 8
    for (int j = 0; j < 128; ++j) {
        float w = row[j];
        s += w * att_src[j];
        d += w * att_dst[j];
    }
    wvs[f] = s; wvd[f] = d;
}

__global__ void k2_logits(const float* __restrict__ x1, const float* __restrict__ x2,
                          const float* __restrict__ wvs, const float* __restrict__ wvd,
                          float* __restrict__ a_s, float* __restrict__ a_d) {
    int wave = blockIdx.x * 4 + (threadIdx.x >> 6);
    int lane = threadIdx.x & 63;
    const float* xrow = (wave < NNODES) ? (x1 + (size_t)wave * 256)
                                        : (x2 + (size_t)(wave - NNODES) * 256);
    float4 xv  = ((const float4*)xrow)[lane];
    float4 wsv = ((const float4*)wvs)[lane];
    float4 wdv = ((const float4*)wvd)[lane];
    float ps = xv.x*wsv.x + xv.y*wsv.y + xv.z*wsv.z + xv.w*wsv.w;
    float pd = xv.x*wdv.x + xv.y*wdv.y + xv.z*wdv.z + xv.w*wdv.w;
    #pragma unroll
    for (int o = 32; o > 0; o >>= 1) {
        ps += __shfl_down(ps, o);
        pd += __shfl_down(pd, o);
    }
    if (lane == 0) { a_s[wave] = ps; a_d[wave] = pd; }
}

__device__ __forceinline__ float lrelu_exp(float e) {
    e = (e > 0.f) ? e : NEG_SLOPE * e;
    return __expf(e);
}

// Pass 1: ex -> d_out (coalesced), per-block LDS segment sums -> partials.
__global__ __launch_bounds__(EK_TPB) void k3_denom(
        const int* __restrict__ ei1, const int* __restrict__ ei2,
        const float* __restrict__ a_s, const float* __restrict__ a_d,
        float* __restrict__ partials, float* __restrict__ out,
        int E1, int g1_blocks) {
    __shared__ float ssum[NNODES];           // 16 KB = 1024 float4
    __shared__ float las[NNODES];            // 16 KB  (32 KB total)
    int t = threadIdx.x;
    int b = blockIdx.x;
    const int* sp; int qbase, nodeoff, outq;
    if (b < g1_blocks) { sp = ei1; qbase = b * EK_QPB; nodeoff = 0; outq = qbase; }
    else { sp = ei2; qbase = (b - g1_blocks) * EK_QPB; nodeoff = NNODES; outq = E1/4 + qbase; }
    const int4* s4 = (const int4*)sp;
    const int4* d4 = (const int4*)(sp + E1);
    const float* adg = a_d + nodeoff;        // a_d gather via L1 (TA pipe)

    // NNODES floats == 1024 float4 == exactly one pass of 1024 threads
    ((float4*)las)[t]  = ((const float4*)(a_s + nodeoff))[t];
    ((float4*)ssum)[t] = make_float4(0.f, 0.f, 0.f, 0.f);
    __syncthreads();

    float4* out4 = (float4*)out;
    #pragma unroll
    for (int k = 0; k < 8; ++k) {
        int q = qbase + (k << 10) + t;
        int4 sv = s4[q];
        int4 dv = d4[q];
        float ad0 = adg[dv.x], ad1 = adg[dv.y], ad2 = adg[dv.z], ad3 = adg[dv.w];
        float e0 = lrelu_exp(las[sv.x] + ad0);
        float e1 = lrelu_exp(las[sv.y] + ad1);
        float e2 = lrelu_exp(las[sv.z] + ad2);
        float e3 = lrelu_exp(las[sv.w] + ad3);
        atomicAdd(&ssum[dv.x], e0);
        atomicAdd(&ssum[dv.y], e1);
        atomicAdd(&ssum[dv.z], e2);
        atomicAdd(&ssum[dv.w], e3);
        out4[outq + (k << 10) + t] = make_float4(e0, e1, e2, e3);
    }
    __syncthreads();
    float* pb = partials + (size_t)b * NNODES;
    ((float4*)pb)[t] = ((float4*)ssum)[t];
}

__global__ void k4a_reduce(const float* __restrict__ partials,
                           float* __restrict__ partials2, int g1_blocks) {
    int tid = blockIdx.x * blockDim.x + threadIdx.x;
    int c  = tid >> 13;
    int sg = tid & (NSEG - 1);
    int bpc = g1_blocks >> 3;
    int b0 = ((sg < NNODES) ? 0 : g1_blocks) + c * bpc;
    int col = sg & (NNODES - 1);
    float s = 0.f;
    for (int j = 0; j < bpc; ++j)
        s += partials[(size_t)(b0 + j) * NNODES + col];
    partials2[tid] = s;
}

__global__ void k4b_inv(const float* __restrict__ partials2,
                        float* __restrict__ inv_denom) {
    int sg = blockIdx.x * blockDim.x + threadIdx.x;
    float s = 0.f;
    #pragma unroll
    for (int c = 0; c < 8; ++c) s += partials2[c * NSEG + sg];
    inv_denom[sg] = 1.0f / s;
}

// Pass 2: alpha = ex * inv_denom[dst], in-place on d_out. One LDS op/edge.
__global__ __launch_bounds__(EK_TPB) void k5_alpha(
        const int* __restrict__ ei1, const int* __restrict__ ei2,
        const float* __restrict__ inv_denom,
        float* __restrict__ out, int E1, int g1_blocks) {
    __shared__ float linv[NNODES];           // 16 KB = 1024 float4
    int t = threadIdx.x;
    int b = blockIdx.x;
    const int* sp; int qbase, nodeoff, outq;
    if (b < g1_blocks) { sp = ei1; qbase = b * EK_QPB; nodeoff = 0; outq = qbase; }
    else { sp = ei2; qbase = (b - g1_blocks) * EK_QPB; nodeoff = NNODES; outq = E1/4 + qbase; }
    const int4* d4 = (const int4*)(sp + E1);

    ((float4*)linv)[t] = ((const float4*)(inv_denom + nodeoff))[t];
    __syncthreads();

    float4* out4 = (float4*)out;
    #pragma unroll
    for (int k = 0; k < 8; ++k) {
        int q = qbase + (k << 10) + t;
        int4  dv = d4[q];
        float4 ex = out4[outq + (k << 10) + t];
        ex.x *= linv[dv.x];
        ex.y *= linv[dv.y];
        ex.z *= linv[dv.z];
        ex.w *= linv[dv.w];
        out4[outq + (k << 10) + t] = ex;
    }
}

extern "C" void kernel_launch(void* const* d_in, const int* in_sizes, int n_in,
                              void* d_out, int out_size, void* d_ws, size_t ws_size,
                              hipStream_t stream) {
    const float* x1      = (const float*)d_in[0];
    const float* x2      = (const float*)d_in[1];
    const int*   ei1     = (const int*)d_in[2];
    const int*   ei2     = (const int*)d_in[3];
    const float* W       = (const float*)d_in[4];
    const float* att_src = (const float*)d_in[5];
    const float* att_dst = (const float*)d_in[6];
    float* out = (float*)d_out;

    const int E1 = in_sizes[2] / 2;          // 8388608 edges per graph

    float* wsf       = (float*)d_ws;
    float* wvs       = wsf;                  // 256
    float* wvd       = wsf + 256;            // 256
    float* a_s       = wsf + 512;            // 8192
    float* a_d       = wsf + 512 + NSEG;     // 8192
    float* inv_denom = wsf + 512 + 2*NSEG;   // 8192
    float* partials2 = wsf + 32768;          // 65536
    float* partials  = wsf + 131072;         // 512*4096 floats (8 MB)

    hipLaunchKernelGGL(k1_wvec, dim3(1), dim3(256), 0, stream,
                       W, att_src, att_dst, wvs, wvd);
    hipLaunchKernelGGL(k2_logits, dim3(2 * NNODES / 4), dim3(256), 0, stream,
                       x1, x2, wvs, wvd, a_s, a_d);

    int g1b = (E1 / 4) / EK_QPB;             // 256 blocks per graph half
    hipLaunchKernelGGL(k3_denom, dim3(2 * g1b), dim3(EK_TPB), 0, stream,
                       ei1, ei2, a_s, a_d, partials, out, E1, g1b);
    hipLaunchKernelGGL(k4a_reduce, dim3(8 * NSEG / 256), dim3(256), 0, stream,
                       partials, partials2, g1b);
    hipLaunchKernelGGL(k4b_inv, dim3(NSEG / 256), dim3(256), 0, stream,
                       partials2, inv_denom);
    hipLaunchKernelGGL(k5_alpha, dim3(2 * g1b), dim3(EK_TPB), 0, stream,
                       ei1, ei2, inv_denom, out, E1, g1b);
}